// Round 1
// baseline (849.563 us; speedup 1.0000x reference)
//
#include <hip/hip_runtime.h>

// Problem constants (match reference setup_inputs)
#define NPOL   2
#define NANT   64
#define NBL    2016
#define NT     64
#define NF     256

constexpr int  TF     = NT * NF;              // 16384 points per (pol-plane, baseline)
constexpr int  TF4    = TF / 4;               // 4096 float4 chunks per baseline
constexpr long VPLANE = (long)NBL * TF;       // stride between (b,c) pol planes of V_m / out
constexpr long JPLANE = (long)NANT * TF;      // stride between (a,b) pol planes of jones

__device__ __forceinline__ float4 f4_mul(float4 a, float4 b) {
    return make_float4(a.x * b.x, a.y * b.y, a.z * b.z, a.w * b.w);
}
__device__ __forceinline__ float4 f4_fma(float4 a, float4 b, float4 c) {
    return make_float4(fmaf(a.x, b.x, c.x), fmaf(a.y, b.y, c.y),
                       fmaf(a.z, b.z, c.z), fmaf(a.w, b.w, c.w));
}

__global__ __launch_bounds__(256) void jones_congruence_kernel(
    const float* __restrict__ V,     // (2,2,NBL,NT,NF)
    const float* __restrict__ J,     // (2,2,NANT,NT,NF)
    const int*   __restrict__ ant1,  // (NBL,)
    const int*   __restrict__ ant2,  // (NBL,)
    float*       __restrict__ out)   // (2,2,NBL,NT,NF)
{
    const int tid = blockIdx.x * blockDim.x + threadIdx.x;   // [0, NBL*TF4)
    const int n   = tid >> 12;                               // TF4 == 4096
    const int r   = tid & (TF4 - 1);

    const long base_v  = (long)n * TF + (long)r * 4;
    const int  a1      = ant1[n];
    const int  a2      = ant2[n];
    const long base_j1 = (long)a1 * TF + (long)r * 4;
    const long base_j2 = (long)a2 * TF + (long)r * 4;

    // V[b][c] (pol plane index b*2+c)
    const float4 v00 = *(const float4*)(V + 0 * VPLANE + base_v);
    const float4 v01 = *(const float4*)(V + 1 * VPLANE + base_v);
    const float4 v10 = *(const float4*)(V + 2 * VPLANE + base_v);
    const float4 v11 = *(const float4*)(V + 3 * VPLANE + base_v);

    // J1[a][b] for antenna a1
    const float4 j1_00 = *(const float4*)(J + 0 * JPLANE + base_j1);
    const float4 j1_01 = *(const float4*)(J + 1 * JPLANE + base_j1);
    const float4 j1_10 = *(const float4*)(J + 2 * JPLANE + base_j1);
    const float4 j1_11 = *(const float4*)(J + 3 * JPLANE + base_j1);

    // J2[d][c] for antenna a2 (conj is identity: real inputs)
    const float4 j2_00 = *(const float4*)(J + 0 * JPLANE + base_j2);
    const float4 j2_01 = *(const float4*)(J + 1 * JPLANE + base_j2);
    const float4 j2_10 = *(const float4*)(J + 2 * JPLANE + base_j2);
    const float4 j2_11 = *(const float4*)(J + 3 * JPLANE + base_j2);

    // W = J1 @ V : W[a][c] = J1[a][0]*V[0][c] + J1[a][1]*V[1][c]
    const float4 w00 = f4_fma(j1_01, v10, f4_mul(j1_00, v00));
    const float4 w01 = f4_fma(j1_01, v11, f4_mul(j1_00, v01));
    const float4 w10 = f4_fma(j1_11, v10, f4_mul(j1_10, v00));
    const float4 w11 = f4_fma(j1_11, v11, f4_mul(j1_10, v01));

    // Out[a][d] = W[a][0]*J2[d][0] + W[a][1]*J2[d][1]
    const float4 o00 = f4_fma(w01, j2_01, f4_mul(w00, j2_00));
    const float4 o01 = f4_fma(w01, j2_11, f4_mul(w00, j2_10));
    const float4 o10 = f4_fma(w11, j2_01, f4_mul(w10, j2_00));
    const float4 o11 = f4_fma(w11, j2_11, f4_mul(w10, j2_10));

    *(float4*)(out + 0 * VPLANE + base_v) = o00;
    *(float4*)(out + 1 * VPLANE + base_v) = o01;
    *(float4*)(out + 2 * VPLANE + base_v) = o10;
    *(float4*)(out + 3 * VPLANE + base_v) = o11;
}

extern "C" void kernel_launch(void* const* d_in, const int* in_sizes, int n_in,
                              void* d_out, int out_size, void* d_ws, size_t ws_size,
                              hipStream_t stream) {
    const float* V    = (const float*)d_in[0];
    const float* J    = (const float*)d_in[1];
    const int*   ant1 = (const int*)d_in[2];
    const int*   ant2 = (const int*)d_in[3];
    float*       out  = (float*)d_out;

    const int total_threads = NBL * TF4;            // 8,257,536
    const int block = 256;
    const int grid  = total_threads / block;        // 32,256 (exact)

    jones_congruence_kernel<<<grid, block, 0, stream>>>(V, J, ant1, ant2, out);
}